// Round 3
// baseline (118.656 us; speedup 1.0000x reference)
//
#include <hip/hip_runtime.h>

// SpatioTemporalGCN: B=64, T=12, N=1024, Ci=64, E=16, K=3, H=192, O=64
// out(b,n,:) = [l2norm(gconv) | l2norm(aconv) | l2norm(wconv)] + bias(n,:)

typedef __attribute__((ext_vector_type(4))) float f32x4;
typedef __attribute__((ext_vector_type(8))) short short8;

#define DEVI static __device__ __forceinline__

DEVI short f2bf(float f) {
    unsigned int x = __builtin_bit_cast(unsigned int, f);
    x = (x + 0x7FFFu + ((x >> 16) & 1u)) >> 16;  // RNE
    return (short)(unsigned short)x;
}
// XOR swizzle: shift in units of 8 shorts (16B slots)
DEVI int swz(int row) { return ((row ^ (row >> 3)) & 7) << 3; }

DEVI f32x4 mfma16(short8 a, short8 b, f32x4 c) {
    return __builtin_amdgcn_mfma_f32_16x16x32_bf16(a, b, c, 0, 0, 0);
}

DEVI void gload16(const void* g, void* l) {
    __builtin_amdgcn_global_load_lds(
        (const __attribute__((address_space(1))) unsigned int*)g,
        (__attribute__((address_space(3))) unsigned int*)l, 16, 0, 0);
}

// ---------------- supports: S = softmax(relu(E E^T), axis=1), bf16 row-major ----------------
__global__ __launch_bounds__(256) void k_supports(const float* __restrict__ NE,
                                                  short* __restrict__ S) {
    int n = blockIdx.x, t = threadIdx.x;
    __shared__ float En[16];
    __shared__ float wsum[4];
    if (t < 16) En[t] = NE[n * 16 + t];
    __syncthreads();
    float e[4];
    float loc = 0.f;
#pragma unroll
    for (int i = 0; i < 4; ++i) {
        int m = t + 256 * i;
        const float* rp = NE + m * 16;
        float v = 0.f;
#pragma unroll
        for (int d = 0; d < 16; ++d) v += En[d] * rp[d];
        v = fmaxf(v, 0.f);
        e[i] = __expf(v);
        loc += e[i];
    }
#pragma unroll
    for (int off = 32; off; off >>= 1) loc += __shfl_xor(loc, off);
    if ((t & 63) == 0) wsum[t >> 6] = loc;
    __syncthreads();
    float inv = 1.f / (wsum[0] + wsum[1] + wsum[2] + wsum[3]);
#pragma unroll
    for (int i = 0; i < 4; ++i) S[n * 1024 + t + 256 * i] = f2bf(e[i] * inv);
}

// ---------------- misc prep: B2 rows, xsum partials, s_bn, A2 rows ----------------
__global__ __launch_bounds__(256) void k_small(
        const float* __restrict__ x, const float* __restrict__ xw,
        const float* __restrict__ NE, const float* __restrict__ adj,
        const float* __restrict__ wp, const float* __restrict__ wpa,
        const float* __restrict__ Tp,
        short* __restrict__ B2, short* __restrict__ A2,
        float* __restrict__ xsp, float* __restrict__ s_bn) {
    __shared__ float red[4][64];
    int bid = blockIdx.x, t = threadIdx.x;
    if (bid < 64) {  // B2 operand rows for o = bid
        int o = bid, j = t;
        short row[64];
        if (j < 192) {
            int kk = j >> 6, i = j & 63;
#pragma unroll
            for (int d = 0; d < 16; ++d)
                row[d] = f2bf(wp[((d * 3 + kk) * 64 + i) * 64 + o]);
#pragma unroll
            for (int k = 16; k < 64; ++k) row[k] = 0;
        } else {
            int i2 = j - 192;
#pragma unroll
            for (int k = 0; k < 16; ++k) row[k] = 0;
#pragma unroll
            for (int d = 0; d < 16; ++d)
#pragma unroll
                for (int kk = 0; kk < 3; ++kk)
                    row[16 + d * 3 + kk] = f2bf(wpa[((d * 3 + kk) * 64 + i2) * 64 + o]);
        }
        short* dst = B2 + (o * 256 + j) * 64;
#pragma unroll
        for (int q = 0; q < 8; ++q) {
            short8 v;
#pragma unroll
            for (int e2 = 0; e2 < 8; ++e2) v[e2] = row[q * 8 + e2];
            *reinterpret_cast<short8*>(dst + q * 8) = v;
        }
    } else if (bid < 320) {  // xsum partials
        int idx = bid - 64, b = idx >> 2, mq = idx & 3;
        int c = t & 63, q2 = t >> 6;
        int m0 = mq * 256 + q2 * 64;
        float s = 0.f;
        for (int mm = 0; mm < 64; ++mm) s += x[(b * 1024 + m0 + mm) * 64 + c];
        red[q2][c] = s;
        __syncthreads();
        if (t < 64) xsp[(b * 4 + mq) * 64 + t] = red[0][t] + red[1][t] + red[2][t] + red[3][t];
    } else if (bid < 336) {  // s_bn[b][n] = sum_t xw[b,t,n]*Tp[t]
        int idx = bid - 320;
        float tp[12];
#pragma unroll
        for (int i = 0; i < 12; ++i) tp[i] = Tp[i];
        for (int bb = 0; bb < 4; ++bb) {
            int b = idx * 4 + bb;
#pragma unroll
            for (int j2 = 0; j2 < 4; ++j2) {
                int nn = t + 256 * j2;
                float s = 0.f;
#pragma unroll
                for (int tt = 0; tt < 12; ++tt) s += xw[(b * 12 + tt) * 1024 + nn] * tp[tt];
                s_bn[b * 1024 + nn] = s;
            }
        }
    } else {  // A2 rows
        int n = (bid - 336) * 256 + t;
        float En[16];
#pragma unroll
        for (int d = 0; d < 16; ++d) En[d] = NE[n * 16 + d];
        float dg[3];
#pragma unroll
        for (int k = 0; k < 3; ++k) dg[k] = adj[k * 1024 * 1024 + n * 1024 + n];
        short row[64];
#pragma unroll
        for (int d = 0; d < 16; ++d) row[d] = f2bf(En[d]);
#pragma unroll
        for (int d = 0; d < 16; ++d)
#pragma unroll
            for (int k = 0; k < 3; ++k) row[16 + d * 3 + k] = f2bf(En[d] * dg[k]);
        short* dst = A2 + n * 64;
#pragma unroll
        for (int q = 0; q < 8; ++q) {
            short8 v;
#pragma unroll
            for (int e2 = 0; e2 < 8; ++e2) v[e2] = row[q * 8 + e2];
            *reinterpret_cast<short8*>(dst + q * 8) = v;
        }
    }
}

// ---------------- prep: transpose x -> XT[j=b*64+c][m], transpose S -> ST, finish xsum ----------------
__global__ __launch_bounds__(256) void k_prep(const float* __restrict__ x,
                                              const short* __restrict__ S,
                                              const float* __restrict__ xsp,
                                              short* __restrict__ ST,
                                              short* __restrict__ XT,
                                              short* __restrict__ xs_bf) {
    __shared__ __align__(16) short Tbuf[64 * 128];
    int bid = blockIdx.x, t = threadIdx.x;
    if (bid < 512) {  // transX: b = bid>>3, m-tile = bid&7 (128 rows)
        int b = bid >> 3, m0 = (bid & 7) * 128;
        const float* xp = x + ((size_t)b * 1024 + m0) * 64;
#pragma unroll
        for (int p = 0; p < 8; ++p) {
            int idx = t + 256 * p;  // 2048 float4s
            int r = idx >> 4, c4 = (idx & 15) * 4;
            float4 v = *reinterpret_cast<const float4*>(&xp[r * 64 + c4]);
            Tbuf[(c4 + 0) * 128 + r] = f2bf(v.x);
            Tbuf[(c4 + 1) * 128 + r] = f2bf(v.y);
            Tbuf[(c4 + 2) * 128 + r] = f2bf(v.z);
            Tbuf[(c4 + 3) * 128 + r] = f2bf(v.w);
        }
        __syncthreads();
#pragma unroll
        for (int p = 0; p < 4; ++p) {
            int idx = t + 256 * p;  // 1024 short8s
            int c = idx >> 4, q = idx & 15;
            *reinterpret_cast<short8*>(&XT[((size_t)b * 64 + c) * 1024 + m0 + q * 8]) =
                *reinterpret_cast<const short8*>(&Tbuf[c * 128 + q * 8]);
        }
    } else if (bid < 768) {  // transS: 64x64 tile (bi,bj) — FULL 64 rows (r2 bug: only 32)
        int idx = bid - 512, bi = idx >> 4, bj = idx & 15;
        int c8 = (t & 7) * 8;
#pragma unroll
        for (int p = 0; p < 2; ++p) {
            int r = (t >> 3) + 32 * p;
            short8 v = *reinterpret_cast<const short8*>(
                &S[(size_t)(bi * 64 + r) * 1024 + bj * 64 + c8]);
#pragma unroll
            for (int e = 0; e < 8; ++e) Tbuf[(c8 + e) * 64 + r] = v[e];
        }
        __syncthreads();
#pragma unroll
        for (int p = 0; p < 2; ++p) {
            int r = (t >> 3) + 32 * p;
            *reinterpret_cast<short8*>(&ST[(size_t)(bj * 64 + r) * 1024 + bi * 64 + c8]) =
                *reinterpret_cast<const short8*>(&Tbuf[r * 64 + c8]);
        }
    } else {  // xs finalize: 16 blocks
        int j = (bid - 768) * 256 + t;
        int b = j >> 6, c = j & 63;
        float s = xsp[(b * 4 + 0) * 64 + c] + xsp[(b * 4 + 1) * 64 + c] +
                  xsp[(b * 4 + 2) * 64 + c] + xsp[(b * 4 + 3) * 64 + c];
        xs_bf[j] = f2bf(s);
    }
}

// ---------------- 128x128 bf16 GEMM tile core (m97-style: global_load_lds, linear LDS) ----------------
DEVI void mm_tile(const short* __restrict__ A, const short* __restrict__ Bt,
                  short* __restrict__ C, int ldC) {
    __shared__ __align__(16) short As[128 * 64];
    __shared__ __align__(16) short Bs[128 * 64];
    int t = threadIdx.x, wid = t >> 6, lane = t & 63;
    int rsub = lane >> 3, csub = (lane & 7) * 8;
    int wm = wid & 1, wn = wid >> 1;
    int lr = lane & 15, lg = lane >> 4;
    f32x4 acc[4][4] = {};
    for (int kt = 0; kt < 16; ++kt) {
#pragma unroll
        for (int q = 0; q < 4; ++q) {
            int row = q * 32 + wid * 8;
            gload16(A + (size_t)(row + rsub) * 1024 + kt * 64 + csub, As + row * 64);
            gload16(Bt + (size_t)(row + rsub) * 1024 + kt * 64 + csub, Bs + row * 64);
        }
        __syncthreads();
#pragma unroll
        for (int ks = 0; ks < 2; ++ks) {
            int kk = ks * 32 + lg * 8;
            short8 af[4], bfv[4];
#pragma unroll
            for (int i = 0; i < 4; ++i)
                af[i] = *reinterpret_cast<const short8*>(&As[(wm * 64 + i * 16 + lr) * 64 + kk]);
#pragma unroll
            for (int i = 0; i < 4; ++i)
                bfv[i] = *reinterpret_cast<const short8*>(&Bs[(wn * 64 + i * 16 + lr) * 64 + kk]);
#pragma unroll
            for (int mf = 0; mf < 4; ++mf)
#pragma unroll
                for (int nf = 0; nf < 4; ++nf)
                    acc[mf][nf] = mfma16(af[mf], bfv[nf], acc[mf][nf]);
        }
        __syncthreads();
    }
#pragma unroll
    for (int mf = 0; mf < 4; ++mf)
#pragma unroll
        for (int nf = 0; nf < 4; ++nf)
#pragma unroll
            for (int r = 0; r < 4; ++r) {
                int g = wm * 64 + mf * 16 + lg * 4 + r;
                int j = wn * 64 + nf * 16 + lr;
                C[(size_t)g * ldC + j] = f2bf(acc[mf][nf][r]);
            }
}

__global__ __launch_bounds__(256) void k_gemmS2(const short* __restrict__ S,
                                                const short* __restrict__ ST,
                                                short* __restrict__ S2) {
    int bx = blockIdx.x, by = blockIdx.y;
    mm_tile(S + (size_t)by * 128 * 1024, ST + (size_t)bx * 128 * 1024,
            S2 + (size_t)by * 128 * 1024 + bx * 128, 1024);
}

__global__ __launch_bounds__(256) void k_gemmY(const short* __restrict__ S,
                                               const short* __restrict__ S2,
                                               const short* __restrict__ XT,
                                               short* __restrict__ Y) {
    int bx = blockIdx.x, by = blockIdx.y;
    const short* A = (by < 8) ? (S + (size_t)by * 128 * 1024)
                              : (S2 + (size_t)(by - 8) * 128 * 1024);
    mm_tile(A, XT + (size_t)bx * 128 * 1024,
            Y + (size_t)by * 128 * 4096 + bx * 128, 4096);
}

// ---------------- Wall = A2 (1024x64) @ B2^T ----------------
__global__ __launch_bounds__(256) void k_gemm_w(const short* __restrict__ A2,
                                                const short* __restrict__ B2,
                                                short* __restrict__ Wall) {
    int bx = blockIdx.x, by = blockIdx.y;
    __shared__ __align__(16) short As[128 * 64];
    __shared__ __align__(16) short Bs[128 * 64];
    int t = threadIdx.x;
#pragma unroll
    for (int i = 0; i < 4; ++i) {
        int slot = t + 256 * i;
        int row = slot >> 3, k8 = slot & 7;
        int sw = swz(row);
        short8 va = *reinterpret_cast<const short8*>(A2 + (by * 128 + row) * 64 + k8 * 8);
        *reinterpret_cast<short8*>(&As[row * 64 + ((k8 * 8) ^ sw)]) = va;
        short8 vb = *reinterpret_cast<const short8*>(B2 + (bx * 128 + row) * 64 + k8 * 8);
        *reinterpret_cast<short8*>(&Bs[row * 64 + ((k8 * 8) ^ sw)]) = vb;
    }
    __syncthreads();
    int w = t >> 6, l = t & 63;
    int wm = w & 1, wn = w >> 1;
    int lr = l & 15, lg = l >> 4;
    f32x4 acc[4][4] = {};
#pragma unroll
    for (int ks = 0; ks < 2; ++ks) {
        int kk = ks * 32 + lg * 8;
        short8 af[4], bfr[4];
#pragma unroll
        for (int mf = 0; mf < 4; ++mf) {
            int row = wm * 64 + mf * 16 + lr;
            af[mf] = *reinterpret_cast<const short8*>(&As[row * 64 + (kk ^ swz(row))]);
        }
#pragma unroll
        for (int nf = 0; nf < 4; ++nf) {
            int row = wn * 64 + nf * 16 + lr;
            bfr[nf] = *reinterpret_cast<const short8*>(&Bs[row * 64 + (kk ^ swz(row))]);
        }
#pragma unroll
        for (int mf = 0; mf < 4; ++mf)
#pragma unroll
            for (int nf = 0; nf < 4; ++nf)
                acc[mf][nf] = mfma16(af[mf], bfr[nf], acc[mf][nf]);
    }
#pragma unroll
    for (int mf = 0; mf < 4; ++mf)
#pragma unroll
        for (int nf = 0; nf < 4; ++nf)
#pragma unroll
            for (int r = 0; r < 4; ++r) {
                int row = by * 128 + wm * 64 + mf * 16 + lg * 4 + r;
                int col = bx * 128 + wn * 64 + nf * 16 + lr;
                Wall[(size_t)row * 16384 + col] = f2bf(acc[mf][nf][r]);
            }
}

// ---------------- epilogue: per-node MFMA (M=64 batch, N=64 O, K=256) + norms + bias ----------------
__global__ __launch_bounds__(256) void k_epi(
        const float* __restrict__ x, const short* __restrict__ Y,
        const short* __restrict__ xs_bf, const float* __restrict__ s_bn,
        const short* __restrict__ Wall, const float* __restrict__ NE,
        const float* __restrict__ bp, const float* __restrict__ wwin,
        float* __restrict__ out) {
    int n = blockIdx.x, t = threadIdx.x;
    __shared__ __align__(16) short Ylds[64 * 256];
    __shared__ float E_l[16];
    __shared__ float bias_l[192];
    __shared__ float ww_l[64];
    __shared__ float sq_l[2][2][64];
    __shared__ float wwn_l;
    if (t < 16) E_l[t] = NE[n * 16 + t];
    __syncthreads();
    if (t < 192) {
        float s = 0.f;
#pragma unroll
        for (int d = 0; d < 16; ++d) s += E_l[d] * bp[d * 192 + t];
        bias_l[t] = s;
    } else {
        int o = t - 192;
        float s = 0.f;
#pragma unroll
        for (int d = 0; d < 16; ++d) s += E_l[d] * wwin[d * 64 + o];
        ww_l[o] = s;
    }
    int w = t >> 6, l = t & 63;
    int wm = w & 1, wn = w >> 1;
    int lr = l & 15, lg = l >> 4;
    // W fragments in VGPRs (B-operand: lane col=o, k=j)
    short8 wf[8][2];
#pragma unroll
    for (int ks = 0; ks < 8; ++ks)
#pragma unroll
        for (int nf = 0; nf < 2; ++nf) {
            int o = wn * 32 + nf * 16 + lr;
            int k = ks * 32 + lg * 8;
            wf[ks][nf] = *reinterpret_cast<const short8*>(Wall + ((size_t)n * 64 + o) * 256 + k);
        }
    // vectorized staging: Ylds[b][k] with k-parts [x | y1 | y2 | xsum]
    const short* y1r = Y + (size_t)n * 4096;
    const short* y2r = Y + (size_t)(1024 + n) * 4096;
#pragma unroll
    for (int it = 0; it < 8; ++it) {
        int part = it >> 1;
        int b = (it & 1) * 32 + (t >> 3);
        int q = t & 7;
        short8 v;
        if (part == 0) {
            const float4* p = reinterpret_cast<const float4*>(&x[((size_t)b * 1024 + n) * 64 + q * 8]);
            float4 p0 = p[0], p1 = p[1];
            v[0] = f2bf(p0.x); v[1] = f2bf(p0.y); v[2] = f2bf(p0.z); v[3] = f2bf(p0.w);
            v[4] = f2bf(p1.x); v[5] = f2bf(p1.y); v[6] = f2bf(p1.z); v[7] = f2bf(p1.w);
        } else if (part == 1) {
            v = *reinterpret_cast<const short8*>(&y1r[b * 64 + q * 8]);
        } else if (part == 2) {
            v = *reinterpret_cast<const short8*>(&y2r[b * 64 + q * 8]);
        } else {
            v = *reinterpret_cast<const short8*>(&xs_bf[b * 64 + q * 8]);
        }
        *reinterpret_cast<short8*>(&Ylds[b * 256 + ((part * 64 + q * 8) ^ swz(b))]) = v;
    }
    __syncthreads();
    if (t < 64) {  // ||ww||
        float v = ww_l[t];
        float s2 = v * v;
#pragma unroll
        for (int off = 32; off; off >>= 1) s2 += __shfl_xor(s2, off);
        if (t == 0) wwn_l = sqrtf(s2);
    }
    f32x4 accg[2][2] = {};
    f32x4 acca[2][2] = {};
#pragma unroll
    for (int ks = 0; ks < 8; ++ks) {
        short8 af[2];
#pragma unroll
        for (int mf = 0; mf < 2; ++mf) {
            int b = wm * 32 + mf * 16 + lr;
            int k = ks * 32 + lg * 8;
            af[mf] = *reinterpret_cast<const short8*>(&Ylds[b * 256 + (k ^ swz(b))]);
        }
#pragma unroll
        for (int mf = 0; mf < 2; ++mf)
#pragma unroll
            for (int nf = 0; nf < 2; ++nf) {
                if (ks < 6) accg[mf][nf] = mfma16(af[mf], wf[ks][nf], accg[mf][nf]);
                else        acca[mf][nf] = mfma16(af[mf], wf[ks][nf], acca[mf][nf]);
            }
    }
#pragma unroll
    for (int mf = 0; mf < 2; ++mf)
#pragma unroll
        for (int r = 0; r < 4; ++r) {
            float sg = accg[mf][0][r] * accg[mf][0][r] + accg[mf][1][r] * accg[mf][1][r];
            float sa = acca[mf][0][r] * acca[mf][0][r] + acca[mf][1][r] * acca[mf][1][r];
#pragma unroll
            for (int off = 1; off < 16; off <<= 1) {
                sg += __shfl_xor(sg, off);
                sa += __shfl_xor(sa, off);
            }
            if (lr == 0) {
                int b = wm * 32 + mf * 16 + lg * 4 + r;
                sq_l[0][wn][b] = sg;
                sq_l[1][wn][b] = sa;
            }
        }
    __syncthreads();
#pragma unroll
    for (int mf = 0; mf < 2; ++mf)
#pragma unroll
        for (int r = 0; r < 4; ++r) {
            int b = wm * 32 + mf * 16 + lg * 4 + r;
            float ig = 1.f / fmaxf(sqrtf(sq_l[0][0][b] + sq_l[0][1][b]), 1e-12f);
            float ia = 1.f / fmaxf(sqrtf(sq_l[1][0][b] + sq_l[1][1][b]), 1e-12f);
            float* po = out + ((size_t)b * 1024 + n) * 192;
#pragma unroll
            for (int nf = 0; nf < 2; ++nf) {
                int o = wn * 32 + nf * 16 + lr;
                po[o]      = accg[mf][nf][r] * ig + bias_l[o];
                po[64 + o] = acca[mf][nf][r] * ia + bias_l[64 + o];
            }
        }
    // wconv
    float wwn = wwn_l;
#pragma unroll
    for (int it = 0; it < 16; ++it) {
        int b = it * 4 + (t >> 6);
        int o = t & 63;
        float s = s_bn[b * 1024 + n];
        float pre = s * ww_l[o];
        float nrm = fabsf(s) * wwn;
        out[((size_t)b * 1024 + n) * 192 + 128 + o] = pre / fmaxf(nrm, 1e-12f) + bias_l[128 + o];
    }
}

extern "C" void kernel_launch(void* const* d_in, const int* in_sizes, int n_in,
                              void* d_out, int out_size, void* d_ws, size_t ws_size,
                              hipStream_t stream) {
    const float* x    = (const float*)d_in[0];
    const float* xw   = (const float*)d_in[1];
    const float* NE   = (const float*)d_in[2];
    const float* adj  = (const float*)d_in[4];
    const float* wp   = (const float*)d_in[5];
    const float* wpa  = (const float*)d_in[6];
    const float* wwin = (const float*)d_in[7];
    const float* bp   = (const float*)d_in[8];
    const float* Tp   = (const float*)d_in[9];
    float* out = (float*)d_out;

    char* ws = (char*)d_ws;
    // lifetimes: S/ST/S2/XT die after k_gemmY; Wall (written by k_gemm_w, launched
    // AFTER k_gemmY) overlays them at offset 0.
    const size_t OFF_S    = 0;           // 2 MB   (also Wall@0: 32 MB, later)
    const size_t OFF_ST   = 2097152;     // 2 MB
    const size_t OFF_S2   = 4194304;     // 2 MB
    const size_t OFF_XT   = 6291456;     // 8 MB
    const size_t OFF_WALL = 0;           // 32 MB  (after S..XT are dead)
    const size_t OFF_Y    = 33554432;    // 16 MB
    const size_t OFF_A2   = 50331648;    // 128 KB
    const size_t OFF_B2   = 50462720;    // 2 MB
    const size_t OFF_XSP  = 52559872;    // 64 KB
    const size_t OFF_XSBF = 52625408;    // 8 KB
    const size_t OFF_SBN  = 52633600;    // 256 KB
    const size_t NEED     = 52895744;
    if (ws_size < NEED) return;  // fails validation loudly

    short* S     = (short*)(ws + OFF_S);
    short* ST    = (short*)(ws + OFF_ST);
    short* S2    = (short*)(ws + OFF_S2);
    short* XT    = (short*)(ws + OFF_XT);
    short* Wall  = (short*)(ws + OFF_WALL);
    short* Y     = (short*)(ws + OFF_Y);
    short* A2    = (short*)(ws + OFF_A2);
    short* B2    = (short*)(ws + OFF_B2);
    float* xsp   = (float*)(ws + OFF_XSP);
    short* xs_bf = (short*)(ws + OFF_XSBF);
    float* s_bn  = (float*)(ws + OFF_SBN);

    k_supports<<<1024, 256, 0, stream>>>(NE, S);
    k_small<<<340, 256, 0, stream>>>(x, xw, NE, adj, wp, wpa, Tp, B2, A2, xsp, s_bn);
    k_prep<<<784, 256, 0, stream>>>(x, S, xsp, ST, XT, xs_bf);
    k_gemmS2<<<dim3(8, 8), 256, 0, stream>>>(S, ST, S2);
    k_gemmY<<<dim3(32, 16), 256, 0, stream>>>(S, S2, XT, Y);
    k_gemm_w<<<dim3(128, 8), 256, 0, stream>>>(A2, B2, Wall);
    k_epi<<<1024, 256, 0, stream>>>(x, Y, xs_bf, s_bn, Wall, NE, bp, wwin, out);
}